// Round 4
// baseline (138.218 us; speedup 1.0000x reference)
//
#include <hip/hip_runtime.h>
#include <math.h>

#define BC 4
#define NODES 4096
#define FEAT 64
#define OUT_DIM 32
#define NWORDS (NODES / 32)        // 128 mask words per row
#define NEG_FILL (-1e16f)
#define MAXNBR 512                 // per-row neighbor cap (Binomial(131072,1/4096); P(>512)~0)

// ---------------------------------------------------------------------------
// Fused prep kernel, grid-partitioned:
//   blocks [0, zblocks):  z[b,n,:] = h[b,n,:] @ W   (float4-vectorized, 8 thr/row)
//   blocks [zblocks, ..): adjacency bitmask from COO (atomicOr dedupes, matching
//                         the reference's .at[r,c].set(1.0) semantics)
// ---------------------------------------------------------------------------
__global__ void prep(const float* __restrict__ h, const float* __restrict__ W,
                     const int* __restrict__ arow, const int* __restrict__ acol,
                     float* __restrict__ z, unsigned int* __restrict__ mask,
                     int n_edges, int zblocks) {
    if ((int)blockIdx.x < zblocks) {
        int t = blockIdx.x * 256 + threadIdx.x;   // < BC*NODES*8
        int g = t & 7;                            // which float4 of the out row
        int row = t >> 3;                         // b*NODES + n
        const float4* hr4 = (const float4*)(h + row * FEAT);  // 16 float4s
        const float4* W4 = (const float4*)W;      // W row f = 8 float4s
        float4 s = make_float4(0.f, 0.f, 0.f, 0.f);
#pragma unroll
        for (int fq = 0; fq < 16; ++fq) {
            float4 hv = hr4[fq];
            float4 w0 = W4[(fq * 4 + 0) * 8 + g];
            float4 w1 = W4[(fq * 4 + 1) * 8 + g];
            float4 w2 = W4[(fq * 4 + 2) * 8 + g];
            float4 w3 = W4[(fq * 4 + 3) * 8 + g];
            s.x = fmaf(hv.x, w0.x, s.x); s.y = fmaf(hv.x, w0.y, s.y);
            s.z = fmaf(hv.x, w0.z, s.z); s.w = fmaf(hv.x, w0.w, s.w);
            s.x = fmaf(hv.y, w1.x, s.x); s.y = fmaf(hv.y, w1.y, s.y);
            s.z = fmaf(hv.y, w1.z, s.z); s.w = fmaf(hv.y, w1.w, s.w);
            s.x = fmaf(hv.z, w2.x, s.x); s.y = fmaf(hv.z, w2.y, s.y);
            s.z = fmaf(hv.z, w2.z, s.z); s.w = fmaf(hv.z, w2.w, s.w);
            s.x = fmaf(hv.w, w3.x, s.x); s.y = fmaf(hv.w, w3.y, s.y);
            s.z = fmaf(hv.w, w3.z, s.z); s.w = fmaf(hv.w, w3.w, s.w);
        }
        ((float4*)z)[t] = s;
    } else {
        int t = ((int)blockIdx.x - zblocks) * 256 + threadIdx.x;
        if (t < n_edges) {
            int r = arow[t], c = acol[t];
            atomicOr(&mask[r * NWORDS + (c >> 5)], 1u << (c & 31));
        }
    }
}

// ---------------------------------------------------------------------------
// gatk v4: per-lane-neighbor with ONLINE MAX (v3's no-max softmax overflowed
// on self-edges: score = ||z_n||^2 ~ 85 +/- 21, exp overflows f32 past 88.7).
//   - 8 half-wave row slots = 2 nodes x 4 batches; compaction once per node.
//   - chunk of 32 neighbors: lane j gathers z-row m_j (8xfloat4) into REGISTERS,
//     s_j = leaky(zn.zm_j); ONE 5-step shfl max-reduce per chunk; alpha is
//     lane-uniform so lsum stays per-lane (no per-chunk sum reduce);
//     acc[k] = p*row[k] + alpha*acc[k]  -- NO aggregation re-load, NO psw
//     staging.
//   - end: 31-step butterfly transpose-reduce => lane l ends with dim-l sum
//     (element index bits == lane bits), + 5-step scalar reduce for lsum.
// VGPR ~110 (row 32 + acc 32) -> launch_bounds(256,4), 4 blocks/CU.
// ---------------------------------------------------------------------------
__global__ __launch_bounds__(256, 4) void gatk(const float* __restrict__ z,
                                               const unsigned int* __restrict__ mask,
                                               float* __restrict__ out) {
    __shared__ unsigned short nbr[2][MAXNBR];
    __shared__ float zns[8][OUT_DIM];
    __shared__ int totals[2];

    int wave = threadIdx.x >> 6;
    int lane = threadIdx.x & 63;
    int sub = lane >> 5;                   // half within wave
    int l = lane & 31;                     // lane within row == output dim
    int r = wave * 2 + sub;                // row slot 0..7
    int nloc = r >> 2;                     // which of the block's 2 nodes
    int b = r & 3;                         // batch
    int n = blockIdx.x * 2 + nloc;
    const float* zb = z + b * NODES * OUT_DIM;

    // ---- phase 1: neighbor compaction, once per node (waves 0/1) ----
    if (wave < 2) {
        int cn = blockIdx.x * 2 + wave;
        uint2 mw = ((const uint2*)(mask + cn * NWORDS))[lane];   // 2 words/lane
        int myc = __popc(mw.x) + __popc(mw.y);
        int pre = myc;
#pragma unroll
        for (int off = 1; off < 64; off <<= 1) {
            int t = __shfl_up(pre, off, 64);
            if (lane >= off) pre += t;
        }
        if (lane == 63) totals[wave] = pre;
        int posi = pre - myc;              // exclusive prefix = write offset
        unsigned short* mn = nbr[wave];
        unsigned int w; int cb = lane * 64;
        w = mw.x; while (w) { int bit = __ffs(w) - 1; w &= w - 1; mn[posi++] = (unsigned short)(cb + bit); }
        cb += 32;
        w = mw.y; while (w) { int bit = __ffs(w) - 1; w &= w - 1; mn[posi++] = (unsigned short)(cb + bit); }
    }
    zns[r][l] = zb[n * OUT_DIM + l];
    __syncthreads();

    int total = totals[nloc];
    const unsigned short* mn = nbr[nloc];
    const float4* zn4 = (const float4*)zns[r];
    const float4* zb4 = (const float4*)zb;

    // ---- phase 2: lane-per-neighbor score + in-register weighted accumulate ----
    float acc[32];
#pragma unroll
    for (int k = 0; k < 32; ++k) acc[k] = 0.f;
    float lsum = 0.f;
    float m_run = -INFINITY;

    for (int base = 0; base < total; base += 32) {
        int j = base + l;
        bool valid = (j < total);
        int mi = valid ? (int)mn[j] : 0;   // always load (p=0 kills the lane)
        const float4* zm4 = zb4 + mi * 8;
        float4 row[8];
#pragma unroll
        for (int q = 0; q < 8; ++q) row[q] = zm4[q];

        float t0 = 0.f, t1 = 0.f, t2 = 0.f, t3 = 0.f;
#pragma unroll
        for (int q = 0; q < 8; ++q) {
            float4 a = zn4[q];             // LDS broadcast within half-wave
            t0 = fmaf(a.x, row[q].x, t0);
            t1 = fmaf(a.y, row[q].y, t1);
            t2 = fmaf(a.z, row[q].z, t2);
            t3 = fmaf(a.w, row[q].w, t3);
        }
        float t = (t0 + t1) + (t2 + t3);
        float s = (t >= 0.f) ? t : 0.1f * t;   // LeakyReLU(0.1)
        if (s == 0.f) s = NEG_FILL;            // masked_fill(att==0, -1e16)
        if (!valid) s = NEG_FILL;              // lane past end of list

        // chunk max (lane-uniform across the 32-lane half-wave)
        float cmax = s;
#pragma unroll
        for (int off = 16; off > 0; off >>= 1)
            cmax = fmaxf(cmax, __shfl_xor(cmax, off, 32));
        float m_new = fmaxf(m_run, cmax);
        float alpha = (m_run == -INFINITY) ? 0.f : __expf(m_run - m_new);
        m_run = m_new;

        float p = __expf(s - m_new);           // bounded by 1; -1e16 -> 0
        lsum = fmaf(lsum, alpha, p);
#pragma unroll
        for (int q = 0; q < 8; ++q) {
            acc[4 * q + 0] = fmaf(p, row[q].x, acc[4 * q + 0] * alpha);
            acc[4 * q + 1] = fmaf(p, row[q].y, acc[4 * q + 1] * alpha);
            acc[4 * q + 2] = fmaf(p, row[q].z, acc[4 * q + 2] * alpha);
            acc[4 * q + 3] = fmaf(p, row[q].w, acc[4 * q + 3] * alpha);
        }
    }

    // ---- transpose-reduce: lane l <- sum_j acc_j[l] (31 shfl + 31 add) ----
#pragma unroll
    for (int off = 16; off >= 1; off >>= 1) {
        bool hi = (l & off) != 0;
#pragma unroll
        for (int i = 0; i < off; ++i) {
            float send = hi ? acc[i] : acc[i + off];
            float recv = __shfl_xor(send, off, 32);
            float keep = hi ? acc[i + off] : acc[i];
            acc[i] = keep + recv;
        }
    }
#pragma unroll
    for (int off = 16; off >= 1; off >>= 1)
        lsum += __shfl_xor(lsum, off, 32);

    float o;
    if (m_run <= -1e15f) {
        // degenerate row (all entries -1e16): reference softmax uniform over 4096
        float ssum = 0.f;
        for (int m2 = 0; m2 < NODES; ++m2)
            ssum += zb[m2 * OUT_DIM + l];
        o = ssum * (1.f / NODES);
    } else {
        o = acc[0] / lsum;
    }
    out[((b << 12) | n) * OUT_DIM + l] = o;
}

// ---------------------------------------------------------------------------
extern "C" void kernel_launch(void* const* d_in, const int* in_sizes, int n_in,
                              void* d_out, int out_size, void* d_ws, size_t ws_size,
                              hipStream_t stream) {
    const float* h  = (const float*)d_in[0];
    const float* W  = (const float*)d_in[1];
    const int*   ar = (const int*)d_in[2];
    const int*   ac = (const int*)d_in[3];
    float* out = (float*)d_out;

    // ws layout: z (2 MB) | mask bitmap (2 MB)
    float* z = (float*)d_ws;
    unsigned int* mask =
        (unsigned int*)((char*)d_ws + (size_t)BC * NODES * OUT_DIM * sizeof(float));
    int n_edges = in_sizes[2];

    int zblocks = (BC * NODES * 8) / 256;          // 512
    int eblocks = (n_edges + 255) / 256;           // 512

    hipMemsetAsync(mask, 0, (size_t)NODES * NWORDS * sizeof(unsigned int), stream);
    prep<<<zblocks + eblocks, 256, 0, stream>>>(h, W, ar, ac, z, mask, n_edges, zblocks);
    gatk<<<NODES / 2, 256, 0, stream>>>(z, mask, out);
}

// Round 5
// 91.318 us; speedup vs baseline: 1.5136x; 1.5136x over previous
//
#include <hip/hip_runtime.h>
#include <math.h>

#define BC 4
#define NODES 4096
#define FEAT 64
#define OUT_DIM 32
#define NWORDS (NODES / 32)        // 128 mask words per row
#define NEG_FILL (-1e16f)
#define MAXNBR 512                 // per-row neighbor cap (Binomial(131072,1/4096); P(>512)~0)

// ---------------------------------------------------------------------------
// Fused prep kernel, grid-partitioned:
//   blocks [0, zblocks):  z[b,n,:] = h[b,n,:] @ W   (float4-vectorized, 8 thr/row)
//   blocks [zblocks, ..): adjacency bitmask from COO (atomicOr dedupes, matching
//                         the reference's .at[r,c].set(1.0) semantics)
// ---------------------------------------------------------------------------
__global__ void prep(const float* __restrict__ h, const float* __restrict__ W,
                     const int* __restrict__ arow, const int* __restrict__ acol,
                     float* __restrict__ z, unsigned int* __restrict__ mask,
                     int n_edges, int zblocks) {
    if ((int)blockIdx.x < zblocks) {
        int t = blockIdx.x * 256 + threadIdx.x;   // < BC*NODES*8
        int g = t & 7;                            // which float4 of the out row
        int row = t >> 3;                         // b*NODES + n
        const float4* hr4 = (const float4*)(h + row * FEAT);  // 16 float4s
        const float4* W4 = (const float4*)W;      // W row f = 8 float4s
        float4 s = make_float4(0.f, 0.f, 0.f, 0.f);
#pragma unroll
        for (int fq = 0; fq < 16; ++fq) {
            float4 hv = hr4[fq];
            float4 w0 = W4[(fq * 4 + 0) * 8 + g];
            float4 w1 = W4[(fq * 4 + 1) * 8 + g];
            float4 w2 = W4[(fq * 4 + 2) * 8 + g];
            float4 w3 = W4[(fq * 4 + 3) * 8 + g];
            s.x = fmaf(hv.x, w0.x, s.x); s.y = fmaf(hv.x, w0.y, s.y);
            s.z = fmaf(hv.x, w0.z, s.z); s.w = fmaf(hv.x, w0.w, s.w);
            s.x = fmaf(hv.y, w1.x, s.x); s.y = fmaf(hv.y, w1.y, s.y);
            s.z = fmaf(hv.y, w1.z, s.z); s.w = fmaf(hv.y, w1.w, s.w);
            s.x = fmaf(hv.z, w2.x, s.x); s.y = fmaf(hv.z, w2.y, s.y);
            s.z = fmaf(hv.z, w2.z, s.z); s.w = fmaf(hv.z, w2.w, s.w);
            s.x = fmaf(hv.w, w3.x, s.x); s.y = fmaf(hv.w, w3.y, s.y);
            s.z = fmaf(hv.w, w3.z, s.z); s.w = fmaf(hv.w, w3.w, s.w);
        }
        ((float4*)z)[t] = s;
    } else {
        int t = ((int)blockIdx.x - zblocks) * 256 + threadIdx.x;
        if (t < n_edges) {
            int r = arow[t], c = acol[t];
            atomicOr(&mask[r * NWORDS + (c >> 5)], 1u << (c & 31));
        }
    }
}

// ---------------------------------------------------------------------------
// gatk v5 == v4 with the butterfly transpose-reduce rewritten so every
// acc[] index is a COMPILE-TIME CONSTANT. v4's nested loop (inner bound =
// outer var) defeated unrolling -> runtime-indexed acc[] -> the whole array
// was demoted to scratch (VGPR_Count=64 confirmed it) -> every chunk-loop
// acc access became a ~200cy scratch round-trip (70us, VALUBusy 78%).
// BFLY(OFF) with literal OFF keeps acc in VGPRs.
// ---------------------------------------------------------------------------
#define BFLY(OFF)                                                   \
    do {                                                            \
        bool hi = (l & OFF) != 0;                                   \
        _Pragma("unroll")                                           \
        for (int i = 0; i < OFF; ++i) {                             \
            float send = hi ? acc[i] : acc[i + OFF];                \
            float recv = __shfl_xor(send, OFF, 32);                 \
            float keep = hi ? acc[i + OFF] : acc[i];                \
            acc[i] = keep + recv;                                   \
        }                                                           \
    } while (0)

__global__ __launch_bounds__(256, 4) void gatk(const float* __restrict__ z,
                                               const unsigned int* __restrict__ mask,
                                               float* __restrict__ out) {
    __shared__ unsigned short nbr[2][MAXNBR];
    __shared__ float zns[8][OUT_DIM];
    __shared__ int totals[2];

    int wave = threadIdx.x >> 6;
    int lane = threadIdx.x & 63;
    int sub = lane >> 5;                   // half within wave
    int l = lane & 31;                     // lane within row == output dim
    int r = wave * 2 + sub;                // row slot 0..7
    int nloc = r >> 2;                     // which of the block's 2 nodes
    int b = r & 3;                         // batch
    int n = blockIdx.x * 2 + nloc;
    const float* zb = z + b * NODES * OUT_DIM;

    // ---- phase 1: neighbor compaction, once per node (waves 0/1) ----
    if (wave < 2) {
        int cn = blockIdx.x * 2 + wave;
        uint2 mw = ((const uint2*)(mask + cn * NWORDS))[lane];   // 2 words/lane
        int myc = __popc(mw.x) + __popc(mw.y);
        int pre = myc;
#pragma unroll
        for (int off = 1; off < 64; off <<= 1) {
            int t = __shfl_up(pre, off, 64);
            if (lane >= off) pre += t;
        }
        if (lane == 63) totals[wave] = pre;
        int posi = pre - myc;              // exclusive prefix = write offset
        unsigned short* mn = nbr[wave];
        unsigned int w; int cb = lane * 64;
        w = mw.x; while (w) { int bit = __ffs(w) - 1; w &= w - 1; mn[posi++] = (unsigned short)(cb + bit); }
        cb += 32;
        w = mw.y; while (w) { int bit = __ffs(w) - 1; w &= w - 1; mn[posi++] = (unsigned short)(cb + bit); }
    }
    zns[r][l] = zb[n * OUT_DIM + l];
    __syncthreads();

    int total = totals[nloc];
    const unsigned short* mn = nbr[nloc];
    const float4* zn4 = (const float4*)zns[r];
    const float4* zb4 = (const float4*)zb;

    // ---- phase 2: lane-per-neighbor score + in-register weighted accumulate ----
    float acc[32];
#pragma unroll
    for (int k = 0; k < 32; ++k) acc[k] = 0.f;
    float lsum = 0.f;
    float m_run = -INFINITY;

    for (int base = 0; base < total; base += 32) {
        int j = base + l;
        bool valid = (j < total);
        int mi = valid ? (int)mn[j] : 0;   // always load (p=0 kills the lane)
        const float4* zm4 = zb4 + mi * 8;
        float4 row[8];
#pragma unroll
        for (int q = 0; q < 8; ++q) row[q] = zm4[q];

        float t0 = 0.f, t1 = 0.f, t2 = 0.f, t3 = 0.f;
#pragma unroll
        for (int q = 0; q < 8; ++q) {
            float4 a = zn4[q];             // LDS broadcast within half-wave
            t0 = fmaf(a.x, row[q].x, t0);
            t1 = fmaf(a.y, row[q].y, t1);
            t2 = fmaf(a.z, row[q].z, t2);
            t3 = fmaf(a.w, row[q].w, t3);
        }
        float t = (t0 + t1) + (t2 + t3);
        float s = (t >= 0.f) ? t : 0.1f * t;   // LeakyReLU(0.1)
        if (s == 0.f) s = NEG_FILL;            // masked_fill(att==0, -1e16)
        if (!valid) s = NEG_FILL;              // lane past end of list

        // chunk max (lane-uniform across the 32-lane half-wave)
        float cmax = s;
#pragma unroll
        for (int off = 16; off > 0; off >>= 1)
            cmax = fmaxf(cmax, __shfl_xor(cmax, off, 32));
        float m_new = fmaxf(m_run, cmax);
        float alpha = (m_run == -INFINITY) ? 0.f : __expf(m_run - m_new);
        m_run = m_new;

        float p = __expf(s - m_new);           // bounded by 1; -1e16 -> 0
        lsum = fmaf(lsum, alpha, p);
#pragma unroll
        for (int q = 0; q < 8; ++q) {
            acc[4 * q + 0] = fmaf(p, row[q].x, acc[4 * q + 0] * alpha);
            acc[4 * q + 1] = fmaf(p, row[q].y, acc[4 * q + 1] * alpha);
            acc[4 * q + 2] = fmaf(p, row[q].z, acc[4 * q + 2] * alpha);
            acc[4 * q + 3] = fmaf(p, row[q].w, acc[4 * q + 3] * alpha);
        }
    }

    // ---- transpose-reduce, all-constant indices: lane l <- sum_j acc_j[l] ----
    BFLY(16); BFLY(8); BFLY(4); BFLY(2); BFLY(1);
#pragma unroll
    for (int off = 16; off >= 1; off >>= 1)
        lsum += __shfl_xor(lsum, off, 32);

    float o;
    if (m_run <= -1e15f) {
        // degenerate row (all entries -1e16): reference softmax uniform over 4096
        float ssum = 0.f;
        for (int m2 = 0; m2 < NODES; ++m2)
            ssum += zb[m2 * OUT_DIM + l];
        o = ssum * (1.f / NODES);
    } else {
        o = acc[0] / lsum;
    }
    out[((b << 12) | n) * OUT_DIM + l] = o;
}

// ---------------------------------------------------------------------------
extern "C" void kernel_launch(void* const* d_in, const int* in_sizes, int n_in,
                              void* d_out, int out_size, void* d_ws, size_t ws_size,
                              hipStream_t stream) {
    const float* h  = (const float*)d_in[0];
    const float* W  = (const float*)d_in[1];
    const int*   ar = (const int*)d_in[2];
    const int*   ac = (const int*)d_in[3];
    float* out = (float*)d_out;

    // ws layout: z (2 MB) | mask bitmap (2 MB)
    float* z = (float*)d_ws;
    unsigned int* mask =
        (unsigned int*)((char*)d_ws + (size_t)BC * NODES * OUT_DIM * sizeof(float));
    int n_edges = in_sizes[2];

    int zblocks = (BC * NODES * 8) / 256;          // 512
    int eblocks = (n_edges + 255) / 256;           // 512

    hipMemsetAsync(mask, 0, (size_t)NODES * NWORDS * sizeof(unsigned int), stream);
    prep<<<zblocks + eblocks, 256, 0, stream>>>(h, W, ar, ac, z, mask, n_edges, zblocks);
    gatk<<<NODES / 2, 256, 0, stream>>>(z, mask, out);
}

// Round 6
// 89.253 us; speedup vs baseline: 1.5486x; 1.0231x over previous
//
#include <hip/hip_runtime.h>
#include <math.h>

#define BC 4
#define NODES 4096
#define FEAT 64
#define OUT_DIM 32
#define NWORDS (NODES / 32)        // 128 mask words per row
#define NEG_FILL (-1e16f)
#define MAXNBR 512                 // per-row neighbor cap (Binomial(131072,1/4096); P(>512)~0)

// ---------------------------------------------------------------------------
// Fused prep kernel, grid-partitioned:
//   blocks [0, zblocks):  z[b,n,:] = h[b,n,:] @ W   (float4-vectorized, 8 thr/row)
//   blocks [zblocks, ..): adjacency bitmask from COO (atomicOr dedupes, matching
//                         the reference's .at[r,c].set(1.0) semantics)
// ---------------------------------------------------------------------------
__global__ void prep(const float* __restrict__ h, const float* __restrict__ W,
                     const int* __restrict__ arow, const int* __restrict__ acol,
                     float* __restrict__ z, unsigned int* __restrict__ mask,
                     int n_edges, int zblocks) {
    if ((int)blockIdx.x < zblocks) {
        int t = blockIdx.x * 256 + threadIdx.x;   // < BC*NODES*8
        int g = t & 7;                            // which float4 of the out row
        int row = t >> 3;                         // b*NODES + n
        const float4* hr4 = (const float4*)(h + row * FEAT);  // 16 float4s
        const float4* W4 = (const float4*)W;      // W row f = 8 float4s
        float4 s = make_float4(0.f, 0.f, 0.f, 0.f);
#pragma unroll
        for (int fq = 0; fq < 16; ++fq) {
            float4 hv = hr4[fq];
            float4 w0 = W4[(fq * 4 + 0) * 8 + g];
            float4 w1 = W4[(fq * 4 + 1) * 8 + g];
            float4 w2 = W4[(fq * 4 + 2) * 8 + g];
            float4 w3 = W4[(fq * 4 + 3) * 8 + g];
            s.x = fmaf(hv.x, w0.x, s.x); s.y = fmaf(hv.x, w0.y, s.y);
            s.z = fmaf(hv.x, w0.z, s.z); s.w = fmaf(hv.x, w0.w, s.w);
            s.x = fmaf(hv.y, w1.x, s.x); s.y = fmaf(hv.y, w1.y, s.y);
            s.z = fmaf(hv.y, w1.z, s.z); s.w = fmaf(hv.y, w1.w, s.w);
            s.x = fmaf(hv.z, w2.x, s.x); s.y = fmaf(hv.z, w2.y, s.y);
            s.z = fmaf(hv.z, w2.z, s.z); s.w = fmaf(hv.z, w2.w, s.w);
            s.x = fmaf(hv.w, w3.x, s.x); s.y = fmaf(hv.w, w3.y, s.y);
            s.z = fmaf(hv.w, w3.z, s.z); s.w = fmaf(hv.w, w3.w, s.w);
        }
        ((float4*)z)[t] = s;
    } else {
        int t = ((int)blockIdx.x - zblocks) * 256 + threadIdx.x;
        if (t < n_edges) {
            int r = arow[t], c = acol[t];
            atomicOr(&mask[r * NWORDS + (c >> 5)], 1u << (c & 31));
        }
    }
}

// ---------------------------------------------------------------------------
// gatk v6: FULLY COALESCED loads (lane = dim everywhere).
// v5's lane-per-neighbor gather made every global_load touch 64 distinct
// cache lines (8 instrs x 32 rows per half-wave, ~256 line-requests/slot,
// re-touching each line 4x since TA can't coalesce across instructions).
// v6: per neighbor j, all 32 lanes read row m_j contiguously (2 lines/instr).
//   pass 1: t[j] = zn[l] * z[m_j][l]  (t[] compile-time indexed -> VGPRs),
//           then ONE 31-shfl butterfly transpose-reduce per chunk:
//           lane j <- s_j = sum_l t_l[j].
//   softmax: in lane=neighbor space (5-shfl max, online rescale).
//   pass 2: p staged in half-wave-private LDS; acc (ONE reg, lane=dim)
//           += p_j * z[m_j][l], coalesced reload (L2-hot).
// Register pressure collapses (no row[8]/acc[32]/zns LDS): target <=64 VGPR
// -> launch_bounds(256,8) -> 32 waves/CU, single dispatch round.
// ---------------------------------------------------------------------------
#define BFLYT(OFF)                                                  \
    do {                                                            \
        bool hi = (l & OFF) != 0;                                   \
        _Pragma("unroll")                                           \
        for (int i = 0; i < OFF; ++i) {                             \
            float send = hi ? tt[i] : tt[i + OFF];                  \
            float recv = __shfl_xor(send, OFF, 32);                 \
            float keep = hi ? tt[i + OFF] : tt[i];                  \
            tt[i] = keep + recv;                                    \
        }                                                           \
    } while (0)

__global__ __launch_bounds__(256, 8) void gatk(const float* __restrict__ z,
                                               const unsigned int* __restrict__ mask,
                                               float* __restrict__ out) {
    __shared__ unsigned short nbr[2][MAXNBR];
    __shared__ float ps[8][32];
    __shared__ int totals[2];

    int wave = threadIdx.x >> 6;
    int lane = threadIdx.x & 63;
    int sub = lane >> 5;                   // half within wave
    int l = lane & 31;                     // lane within row == output dim
    int r = wave * 2 + sub;                // row slot 0..7
    int nloc = r >> 2;                     // which of the block's 2 nodes
    int b = r & 3;                         // batch
    int n = blockIdx.x * 2 + nloc;
    const float* zb = z + b * NODES * OUT_DIM;

    // ---- phase 1: neighbor compaction, once per node (waves 0/1) ----
    if (wave < 2) {
        int cn = blockIdx.x * 2 + wave;
        uint2 mw = ((const uint2*)(mask + cn * NWORDS))[lane];   // 2 words/lane
        int myc = __popc(mw.x) + __popc(mw.y);
        int pre = myc;
#pragma unroll
        for (int off = 1; off < 64; off <<= 1) {
            int t = __shfl_up(pre, off, 64);
            if (lane >= off) pre += t;
        }
        if (lane == 63) totals[wave] = pre;
        int posi = pre - myc;              // exclusive prefix = write offset
        unsigned short* mn = nbr[wave];
        unsigned int w; int cb = lane * 64;
        w = mw.x; while (w) { int bit = __ffs(w) - 1; w &= w - 1; mn[posi++] = (unsigned short)(cb + bit); }
        cb += 32;
        w = mw.y; while (w) { int bit = __ffs(w) - 1; w &= w - 1; mn[posi++] = (unsigned short)(cb + bit); }
    }
    float znl = zb[n * OUT_DIM + l];       // my dim of my node's row (coalesced)
    __syncthreads();

    int total = totals[nloc];
    const unsigned short* mn = nbr[nloc];
    float* psw = ps[r];

    float acc = 0.f;                       // lane=dim accumulator (ONE register)
    float lsum = 0.f;
    float m_run = -INFINITY;

    for (int base = 0; base < total; base += 32) {
        int lim = min(32, total - base);
        const unsigned short* mb = mn + base;

        // ---- pass 1: coalesced row loads, per-lane partial products ----
        float tt[32];
#pragma unroll
        for (int j = 0; j < 32; ++j) {
            int mi = (j < lim) ? (int)mb[j] : 0;     // uniform LDS broadcast
            tt[j] = znl * zb[mi * OUT_DIM + l];      // 128B coalesced / half-wave
        }

        // ---- transpose-reduce: lane j <- s_j = sum over lanes of tt[j] ----
        BFLYT(16); BFLYT(8); BFLYT(4); BFLYT(2); BFLYT(1);
        float s = tt[0];
        s = (s >= 0.f) ? s : 0.1f * s;         // LeakyReLU(0.1)
        if (s == 0.f) s = NEG_FILL;            // masked_fill(att==0, -1e16)
        if (l >= lim) s = NEG_FILL;            // lane past end of list

        // ---- online softmax (lane = neighbor) ----
        float cmax = s;
#pragma unroll
        for (int off = 16; off > 0; off >>= 1)
            cmax = fmaxf(cmax, __shfl_xor(cmax, off, 32));
        float m_new = fmaxf(m_run, cmax);
        float alpha = (m_run == -INFINITY) ? 0.f : __expf(m_run - m_new);
        m_run = m_new;
        float p = __expf(s - m_new);           // bounded by 1; -1e16 -> 0
        float psum = p;
#pragma unroll
        for (int off = 16; off > 0; off >>= 1)
            psum += __shfl_xor(psum, off, 32);
        lsum = fmaf(lsum, alpha, psum);
        acc *= alpha;

        // ---- pass 2: coalesced weighted aggregation (p via LDS broadcast) ----
        psw[l] = p;                            // half-wave private; wave-ordered
        int jj = 0;
        while (jj + 3 < lim) {
            float p0 = psw[jj], p1 = psw[jj + 1], p2 = psw[jj + 2], p3 = psw[jj + 3];
            int m0 = mb[jj], m1 = mb[jj + 1], m2 = mb[jj + 2], m3 = mb[jj + 3];
            float v0 = zb[m0 * OUT_DIM + l];
            float v1 = zb[m1 * OUT_DIM + l];
            float v2 = zb[m2 * OUT_DIM + l];
            float v3 = zb[m3 * OUT_DIM + l];
            acc = fmaf(p0, v0, acc);
            acc = fmaf(p1, v1, acc);
            acc = fmaf(p2, v2, acc);
            acc = fmaf(p3, v3, acc);
            jj += 4;
        }
        while (jj < lim) {
            acc = fmaf(psw[jj], zb[mb[jj] * OUT_DIM + l], acc);
            ++jj;
        }
    }

    float o;
    if (m_run <= -1e15f) {
        // degenerate row (all entries -1e16): reference softmax uniform over 4096
        float ssum = 0.f;
        for (int m2 = 0; m2 < NODES; ++m2)
            ssum += zb[m2 * OUT_DIM + l];
        o = ssum * (1.f / NODES);
    } else {
        o = acc / lsum;
    }
    out[((b << 12) | n) * OUT_DIM + l] = o;
}

// ---------------------------------------------------------------------------
extern "C" void kernel_launch(void* const* d_in, const int* in_sizes, int n_in,
                              void* d_out, int out_size, void* d_ws, size_t ws_size,
                              hipStream_t stream) {
    const float* h  = (const float*)d_in[0];
    const float* W  = (const float*)d_in[1];
    const int*   ar = (const int*)d_in[2];
    const int*   ac = (const int*)d_in[3];
    float* out = (float*)d_out;

    // ws layout: z (2 MB) | mask bitmap (2 MB)
    float* z = (float*)d_ws;
    unsigned int* mask =
        (unsigned int*)((char*)d_ws + (size_t)BC * NODES * OUT_DIM * sizeof(float));
    int n_edges = in_sizes[2];

    int zblocks = (BC * NODES * 8) / 256;          // 512
    int eblocks = (n_edges + 255) / 256;           // 512

    hipMemsetAsync(mask, 0, (size_t)NODES * NWORDS * sizeof(unsigned int), stream);
    prep<<<zblocks + eblocks, 256, 0, stream>>>(h, W, ar, ac, z, mask, n_edges, zblocks);
    gatk<<<NODES / 2, 256, 0, stream>>>(z, mask, out);
}